// Round 1
// baseline (647.283 us; speedup 1.0000x reference)
//
#include <hip/hip_runtime.h>
#include <stdint.h>

#define S_LEN 256
#define DIM   128
#define EPSL  1e-5f

typedef __bf16 bf16x8 __attribute__((ext_vector_type(8)));
typedef float  f32x4  __attribute__((ext_vector_type(4)));

__device__ __forceinline__ unsigned short f2bf_bits(float f) {
  union { float f; unsigned int u; } v; v.f = f;
  unsigned int r = v.u + 0x7fffu + ((v.u >> 16) & 1u);   // RTNE
  return (unsigned short)(r >> 16);
}
__device__ __forceinline__ float bf2f_bits(unsigned short b) {
  union { float f; unsigned int u; } v; v.u = ((unsigned int)b) << 16; return v.f;
}

union Frag8 { unsigned short us[8]; bf16x8 v; int4 i4; };

// Block: 512 thr = 8 waves. Waves 0-3: recurrence via MFMA (W frags in VGPRs).
// Waves 4-7: one step behind -- LN1, proj2, RNN2, LN2, pool + e-gather staging.
// One barrier per step; 2-deep rings on h/e make every hazard cross it.
__global__ __launch_bounds__(512, 2)
void rnn_fused(const int* __restrict__ x,
               const float* __restrict__ emb,
               const float* __restrict__ Wih1,
               const float* __restrict__ bih1,
               const float* __restrict__ Whh1,
               const float* __restrict__ bhh1,
               const float* __restrict__ g1,
               const float* __restrict__ be1,
               const float* __restrict__ Wih2,
               const float* __restrict__ bih2,
               const float* __restrict__ Whh2,
               const float* __restrict__ bhh2,
               const float* __restrict__ g2,
               const float* __restrict__ be2,
               float* __restrict__ out)
{
  // element (row m, channel c) lives at m*128 + ((c>>3) ^ (m&15))*8 + (c&7)
  __shared__ __align__(16) unsigned short h_bf[2][16 * 128];   // 8 KB
  __shared__ __align__(16) unsigned short e_bf[2][16 * 128];   // 8 KB
  __shared__ int x_tile[16 * 256];                             // 16 KB

  const int tid  = threadIdx.x;
  const int wave = tid >> 6;
  const int lane = tid & 63;
  const int r0   = blockIdx.x * 16;
  const int l15  = lane & 15;
  const int q    = lane >> 4;

  for (int i = tid; i < 16 * 256; i += 512)
    x_tile[i] = x[(size_t)(r0 + (i >> 8)) * S_LEN + (i & 255)];
  for (int i = tid; i < 16 * 128; i += 512) h_bf[1][i] = 0;   // h_{-1} = 0

  const bool is_prod = (wave < 4);

  // ---- producer state: W fragments resident in VGPRs (never re-read) ----
  bf16x8 wih[2][4], whi[2][4], wlo[2][4];
  float bias1v[2];
  // ---- consumer state ----
  float g1v[8], be1v[8], w2v[5][8];
  float whh2v[5][5], t2v[5], g2v[5], be2v[5], h2s[5], poolv[5];
  int myrow = 0;
  bool lead = false;

  if (is_prod) {
    // B-frag layout: lane holds B[k = kt*32 + q*8 + j][n = nt*16 + l15] = W[n][k]
#pragma unroll
    for (int ntL = 0; ntL < 2; ntL++) {
      int n = (wave * 2 + ntL) * 16 + l15;
      bias1v[ntL] = bih1[n] + bhh1[n];
#pragma unroll
      for (int kt = 0; kt < 4; kt++) {
        int k0 = kt * 32 + q * 8;
        Frag8 fa, fh, fl;
#pragma unroll
        for (int j = 0; j < 8; j++) {
          fa.us[j] = f2bf_bits(Wih1[n * DIM + k0 + j]);
          float w = Whh1[n * DIM + k0 + j];
          unsigned short hi = f2bf_bits(w);
          fh.us[j] = hi;
          fl.us[j] = f2bf_bits(w - bf2f_bits(hi));   // split-bf16 compensation
        }
        wih[ntL][kt] = fa.v; whi[ntL][kt] = fh.v; wlo[ntL][kt] = fl.v;
      }
    }
  } else {
    myrow = (wave - 4) * 4 + q;        // 16 lanes per row, rows wave-local
    lead  = (l15 == 0);
#pragma unroll
    for (int i = 0; i < 8; i++) {
      int c = l15 + 16 * i;
      g1v[i] = g1[c]; be1v[i] = be1[c];
#pragma unroll
      for (int j = 0; j < 5; j++) w2v[j][i] = Wih2[j * DIM + c];
    }
#pragma unroll
    for (int j = 0; j < 5; j++) {
      t2v[j] = bih2[j] + bhh2[j];
      g2v[j] = g2[j]; be2v[j] = be2[j];
      h2s[j] = 0.f; poolv[j] = 0.f;
#pragma unroll
      for (int jj = 0; jj < 5; jj++) whh2v[j][jj] = Whh2[j * 5 + jj];
    }
  }

  __syncthreads();

  if (!is_prod) {                        // stage e[0] into ring buf 0
    int ti2 = tid - 256;
    int m = ti2 >> 4, oct = ti2 & 15;
    int xid = x_tile[m * 256];
    const float* pe = emb + (size_t)xid * DIM + oct * 8;
    Frag8 pk;
#pragma unroll
    for (int j = 0; j < 8; j++) pk.us[j] = f2bf_bits(pe[j]);
    *(int4*)&e_bf[0][m * 128 + ((oct ^ m) & 15) * 8] = pk.i4;
  }
  __syncthreads();

  for (int t = 0; t <= S_LEN; t++) {
    if (is_prod) {
      if (t < S_LEN) {
        const int rb = (t + 1) & 1;      // h_{t-1} buffer
        const int eb = t & 1;            // e_t buffer
        f32x4 acc0 = {0.f, 0.f, 0.f, 0.f}, acc1 = {0.f, 0.f, 0.f, 0.f};
#pragma unroll
        for (int kt = 0; kt < 4; kt++) {
          int sw = (((kt * 4 + q) ^ l15) & 15) * 8;
          bf16x8 ae = *(const bf16x8*)&e_bf[eb][l15 * 128 + sw];
          bf16x8 ah = *(const bf16x8*)&h_bf[rb][l15 * 128 + sw];
          acc0 = __builtin_amdgcn_mfma_f32_16x16x32_bf16(ae, wih[0][kt], acc0, 0, 0, 0);
          acc1 = __builtin_amdgcn_mfma_f32_16x16x32_bf16(ae, wih[1][kt], acc1, 0, 0, 0);
          acc0 = __builtin_amdgcn_mfma_f32_16x16x32_bf16(ah, whi[0][kt], acc0, 0, 0, 0);
          acc1 = __builtin_amdgcn_mfma_f32_16x16x32_bf16(ah, whi[1][kt], acc1, 0, 0, 0);
          acc0 = __builtin_amdgcn_mfma_f32_16x16x32_bf16(ah, wlo[0][kt], acc0, 0, 0, 0);
          acc1 = __builtin_amdgcn_mfma_f32_16x16x32_bf16(ah, wlo[1][kt], acc1, 0, 0, 0);
        }
        const int wb = t & 1;            // h_t buffer
#pragma unroll
        for (int ntL = 0; ntL < 2; ntL++) {
          int c = (wave * 2 + ntL) * 16 + l15;
          int oct = c >> 3;
#pragma unroll
          for (int r = 0; r < 4; r++) {  // D-layout: row = q*4 + reg, col = l15
            int row = q * 4 + r;
            float av = (ntL ? acc1[r] : acc0[r]) + bias1v[ntL];
            h_bf[wb][row * 128 + ((oct ^ row) & 15) * 8 + (c & 7)] = f2bf_bits(tanhf(av));
          }
        }
      }
    } else {
      if (t < S_LEN - 1) {               // stage e[t+1]
        int ti2 = tid - 256;
        int m = ti2 >> 4, oct = ti2 & 15;
        int xid = x_tile[m * 256 + t + 1];
        const float* pe = emb + (size_t)xid * DIM + oct * 8;
        Frag8 pk;
#pragma unroll
        for (int j = 0; j < 8; j++) pk.us[j] = f2bf_bits(pe[j]);
        *(int4*)&e_bf[(t + 1) & 1][m * 128 + ((oct ^ m) & 15) * 8] = pk.i4;
      }
      if (t >= 1) {                      // process h_{t-1}
        const int hb = (t - 1) & 1;
        float hv[8]; float s = 0.f, sq = 0.f;
#pragma unroll
        for (int i = 0; i < 8; i++) {
          int c = l15 + 16 * i;
          float v = bf2f_bits(h_bf[hb][myrow * 128 + (((c >> 3) ^ myrow) & 15) * 8 + (c & 7)]);
          hv[i] = v; s += v; sq += v * v;
        }
#pragma unroll
        for (int mk = 1; mk < 16; mk <<= 1) {   // LN1 stats: 16-lane reduce
          s  += __shfl_xor(s,  mk, 64);
          sq += __shfl_xor(sq, mk, 64);
        }
        float mean = s * (1.f / 128.f);
        float var  = sq * (1.f / 128.f) - mean * mean;
        float rstd = rsqrtf(var + EPSL);
        float p[5] = {0, 0, 0, 0, 0};
#pragma unroll
        for (int i = 0; i < 8; i++) {
          float z = (hv[i] - mean) * rstd * g1v[i] + be1v[i];
#pragma unroll
          for (int j = 0; j < 5; j++) p[j] = fmaf(w2v[j][i], z, p[j]);
        }
#pragma unroll
        for (int mk = 1; mk < 16; mk <<= 1) {
#pragma unroll
          for (int j = 0; j < 5; j++) p[j] += __shfl_xor(p[j], mk, 64);
        }
        if (lead) {                      // RNN2 + LN2 + pool, one lane per row
          float xn[5];
#pragma unroll
          for (int j = 0; j < 5; j++) {
            float a = p[j] + t2v[j];
#pragma unroll
            for (int jj = 0; jj < 5; jj++) a = fmaf(whh2v[j][jj], h2s[jj], a);
            xn[j] = tanhf(a);
          }
          float m2 = 0.f;
#pragma unroll
          for (int j = 0; j < 5; j++) m2 += xn[j];
          m2 *= 0.2f;
          float v2 = 0.f;
#pragma unroll
          for (int j = 0; j < 5; j++) { float d = xn[j] - m2; v2 += d * d; }
          v2 *= 0.2f;
          float r2 = rsqrtf(v2 + EPSL);
#pragma unroll
          for (int j = 0; j < 5; j++) {
            poolv[j] += (xn[j] - m2) * r2 * g2v[j] + be2v[j];
            h2s[j] = xn[j];
          }
        }
      }
    }
    __syncthreads();   // the single per-step barrier (uniform flow)
  }

  if (!is_prod && lead) {
    float lg[5], mx = -1e30f;
#pragma unroll
    for (int j = 0; j < 5; j++) { lg[j] = poolv[j] * (1.f / 256.f); mx = fmaxf(mx, lg[j]); }
    float sm = 0.f, ex[5];
#pragma unroll
    for (int j = 0; j < 5; j++) { ex[j] = expf(lg[j] - mx); sm += ex[j]; }
    float inv = 1.f / sm;
#pragma unroll
    for (int j = 0; j < 5; j++) out[(size_t)(r0 + myrow) * 5 + j] = ex[j] * inv;
  }
}

extern "C" void kernel_launch(void* const* d_in, const int* in_sizes, int n_in,
                              void* d_out, int out_size, void* d_ws, size_t ws_size,
                              hipStream_t stream) {
  (void)in_sizes; (void)n_in; (void)d_ws; (void)ws_size; (void)out_size;
  rnn_fused<<<dim3(64), dim3(512), 0, stream>>>(
      (const int*)  d_in[0],  (const float*)d_in[1],  (const float*)d_in[2],
      (const float*)d_in[3],  (const float*)d_in[4],  (const float*)d_in[5],
      (const float*)d_in[6],  (const float*)d_in[7],  (const float*)d_in[8],
      (const float*)d_in[9],  (const float*)d_in[10], (const float*)d_in[11],
      (const float*)d_in[12], (const float*)d_in[13], (float*)d_out);
}

// Round 2
// 406.568 us; speedup vs baseline: 1.5921x; 1.5921x over previous
//
#include <hip/hip_runtime.h>
#include <stdint.h>

#define S_LEN 256
#define DIM   128
#define EPSL  1e-5f

typedef __bf16 bf16x8 __attribute__((ext_vector_type(8)));
typedef float  f32x4  __attribute__((ext_vector_type(4)));

__device__ __forceinline__ unsigned short f2bf_bits(float f) {
  union { float f; unsigned int u; } v; v.f = f;
  unsigned int r = v.u + 0x7fffu + ((v.u >> 16) & 1u);   // RTNE
  return (unsigned short)(r >> 16);
}
__device__ __forceinline__ float bf2f_bits(unsigned short b) {
  union { float f; unsigned int u; } v; v.u = ((unsigned int)b) << 16; return v.f;
}
// tanh(x) = 1 - 2/(e^{2x}+1): v_exp + v_rcp, exact at +-inf, ~1e-6 rel err.
// Replaces branchy libm tanhf (~60-100 instr) that dominated R1's critical path.
__device__ __forceinline__ float tanh_fast(float x) {
  float e = __expf(2.f * x);
  return 1.f - 2.f * __builtin_amdgcn_rcpf(e + 1.f);
}

union Frag8 { unsigned short us[8]; bf16x8 v; int4 i4; };

// Block: 512 thr = 8 waves. Waves 0-3: recurrence via MFMA (W frags in VGPRs).
// Waves 4-7: one step behind -- LN1, proj2, RNN2, LN2, pool + e-gather staging.
// One barrier per step; 2-deep rings on h/e make every hazard cross it.
__global__ __launch_bounds__(512, 2)
void rnn_fused(const int* __restrict__ x,
               const float* __restrict__ emb,
               const float* __restrict__ Wih1,
               const float* __restrict__ bih1,
               const float* __restrict__ Whh1,
               const float* __restrict__ bhh1,
               const float* __restrict__ g1,
               const float* __restrict__ be1,
               const float* __restrict__ Wih2,
               const float* __restrict__ bih2,
               const float* __restrict__ Whh2,
               const float* __restrict__ bhh2,
               const float* __restrict__ g2,
               const float* __restrict__ be2,
               float* __restrict__ out)
{
  // element (row m, channel c) lives at m*128 + ((c>>3) ^ (m&15))*8 + (c&7)
  __shared__ __align__(16) unsigned short h_bf[2][16 * 128];   // 8 KB
  __shared__ __align__(16) unsigned short e_bf[2][16 * 128];   // 8 KB
  __shared__ int x_tile[16 * 256];                             // 16 KB

  const int tid  = threadIdx.x;
  const int wave = tid >> 6;
  const int lane = tid & 63;
  const int r0   = blockIdx.x * 16;
  const int l15  = lane & 15;
  const int q    = lane >> 4;

  for (int i = tid; i < 16 * 256; i += 512)
    x_tile[i] = x[(size_t)(r0 + (i >> 8)) * S_LEN + (i & 255)];
  for (int i = tid; i < 16 * 128; i += 512) h_bf[1][i] = 0;   // h_{-1} = 0

  const bool is_prod = (wave < 4);

  // ---- producer state: W fragments resident in VGPRs (never re-read) ----
  bf16x8 wih[2][4], whi[2][4], wlo[2][4];
  float bias1v[2];
  // ---- consumer state ----
  float g1v[8], be1v[8], w2v[5][8];
  float whh2v[5][5], t2v[5], g2v[5], be2v[5], h2s[5], poolv[5];
  int myrow = 0;
  bool lead = false;

  if (is_prod) {
    // B-frag layout: lane holds B[k = kt*32 + q*8 + j][n = nt*16 + l15] = W[n][k]
#pragma unroll
    for (int ntL = 0; ntL < 2; ntL++) {
      int n = (wave * 2 + ntL) * 16 + l15;
      bias1v[ntL] = bih1[n] + bhh1[n];
#pragma unroll
      for (int kt = 0; kt < 4; kt++) {
        int k0 = kt * 32 + q * 8;
        Frag8 fa, fh, fl;
#pragma unroll
        for (int j = 0; j < 8; j++) {
          fa.us[j] = f2bf_bits(Wih1[n * DIM + k0 + j]);
          float w = Whh1[n * DIM + k0 + j];
          unsigned short hi = f2bf_bits(w);
          fh.us[j] = hi;
          fl.us[j] = f2bf_bits(w - bf2f_bits(hi));   // split-bf16 compensation
        }
        wih[ntL][kt] = fa.v; whi[ntL][kt] = fh.v; wlo[ntL][kt] = fl.v;
      }
    }
  } else {
    myrow = (wave - 4) * 4 + q;        // 16 lanes per row, rows wave-local
    lead  = (l15 == 0);
    // This lane will read the b128 at storage oct l15 -> channels (l15^myrow)*8+j.
    int coct = (l15 ^ myrow) & 15;
#pragma unroll
    for (int j = 0; j < 8; j++) {
      int c = coct * 8 + j;
      g1v[j] = g1[c]; be1v[j] = be1[c];
#pragma unroll
      for (int jj = 0; jj < 5; jj++) w2v[jj][j] = Wih2[jj * DIM + c];
    }
#pragma unroll
    for (int j = 0; j < 5; j++) {
      t2v[j] = bih2[j] + bhh2[j];
      g2v[j] = g2[j]; be2v[j] = be2[j];
      h2s[j] = 0.f; poolv[j] = 0.f;
#pragma unroll
      for (int jj = 0; jj < 5; jj++) whh2v[j][jj] = Whh2[j * 5 + jj];
    }
  }

  __syncthreads();

  if (!is_prod) {                        // stage e[0] into ring buf 0
    int ti2 = tid - 256;
    int m = ti2 >> 4, oct = ti2 & 15;
    int xid = x_tile[m * 256];
    const float* pe = emb + (size_t)xid * DIM + oct * 8;
    Frag8 pk;
#pragma unroll
    for (int j = 0; j < 8; j++) pk.us[j] = f2bf_bits(pe[j]);
    *(int4*)&e_bf[0][m * 128 + ((oct ^ m) & 15) * 8] = pk.i4;
  }
  __syncthreads();

  for (int t = 0; t <= S_LEN; t++) {
    if (is_prod) {
      if (t < S_LEN) {
        const int rb = (t + 1) & 1;      // h_{t-1} buffer
        const int eb = t & 1;            // e_t buffer
        // 6 independent accumulator chains (depth 4) instead of 2 (depth 12):
        // MFMA issue-bound, not dependent-latency-bound.
        f32x4 ac_e[2], ac_h[2], ac_l[2];
#pragma unroll
        for (int u = 0; u < 2; u++) {
          ac_e[u] = f32x4{0.f, 0.f, 0.f, 0.f};
          ac_h[u] = f32x4{0.f, 0.f, 0.f, 0.f};
          ac_l[u] = f32x4{0.f, 0.f, 0.f, 0.f};
        }
#pragma unroll
        for (int kt = 0; kt < 4; kt++) {
          int sw = (((kt * 4 + q) ^ l15) & 15) * 8;
          bf16x8 ae = *(const bf16x8*)&e_bf[eb][l15 * 128 + sw];
          bf16x8 ah = *(const bf16x8*)&h_bf[rb][l15 * 128 + sw];
          ac_e[0] = __builtin_amdgcn_mfma_f32_16x16x32_bf16(ae, wih[0][kt], ac_e[0], 0, 0, 0);
          ac_e[1] = __builtin_amdgcn_mfma_f32_16x16x32_bf16(ae, wih[1][kt], ac_e[1], 0, 0, 0);
          ac_h[0] = __builtin_amdgcn_mfma_f32_16x16x32_bf16(ah, whi[0][kt], ac_h[0], 0, 0, 0);
          ac_h[1] = __builtin_amdgcn_mfma_f32_16x16x32_bf16(ah, whi[1][kt], ac_h[1], 0, 0, 0);
          ac_l[0] = __builtin_amdgcn_mfma_f32_16x16x32_bf16(ah, wlo[0][kt], ac_l[0], 0, 0, 0);
          ac_l[1] = __builtin_amdgcn_mfma_f32_16x16x32_bf16(ah, wlo[1][kt], ac_l[1], 0, 0, 0);
        }
        const int wb = t & 1;            // h_t buffer
#pragma unroll
        for (int ntL = 0; ntL < 2; ntL++) {
          int c = (wave * 2 + ntL) * 16 + l15;
          int oct = c >> 3;
#pragma unroll
          for (int r = 0; r < 4; r++) {  // D-layout: row = q*4 + reg, col = l15
            int row = q * 4 + r;
            float av = ac_e[ntL][r] + ac_h[ntL][r] + ac_l[ntL][r] + bias1v[ntL];
            h_bf[wb][row * 128 + ((oct ^ row) & 15) * 8 + (c & 7)] = f2bf_bits(tanh_fast(av));
          }
        }
      }
    } else {
      const int ti2 = tid - 256;
      const int m   = ti2 >> 4;
      const int oct = ti2 & 15;
      // Issue gather loads for e[t+1] FIRST; consume at end of step so the
      // ~300-900cy global latency overlaps the LN1/RNN2 work below.
      float pf[8];
      if (t < S_LEN - 1) {
        int xid = x_tile[m * 256 + t + 1];
        const float* pe = emb + (size_t)xid * DIM + oct * 8;
#pragma unroll
        for (int j = 0; j < 8; j++) pf[j] = pe[j];
      }
      if (t >= 1) {                      // process h_{t-1}
        const int hb = (t - 1) & 1;
        Frag8 hr;                        // one b128 instead of 8 ds_read_u16
        hr.i4 = *(const int4*)&h_bf[hb][myrow * 128 + l15 * 8];
        float hv[8]; float s = 0.f, sq = 0.f;
#pragma unroll
        for (int j = 0; j < 8; j++) {
          float v = bf2f_bits(hr.us[j]);
          hv[j] = v; s += v; sq += v * v;
        }
#pragma unroll
        for (int mk = 1; mk < 16; mk <<= 1) {   // LN1 stats: 16-lane reduce
          s  += __shfl_xor(s,  mk, 64);
          sq += __shfl_xor(sq, mk, 64);
        }
        float mean = s * (1.f / 128.f);
        float var  = sq * (1.f / 128.f) - mean * mean;
        float rstd = rsqrtf(var + EPSL);
        float p[5] = {0, 0, 0, 0, 0};
#pragma unroll
        for (int j = 0; j < 8; j++) {
          float z = (hv[j] - mean) * rstd * g1v[j] + be1v[j];
#pragma unroll
          for (int jj = 0; jj < 5; jj++) p[jj] = fmaf(w2v[jj][j], z, p[jj]);
        }
#pragma unroll
        for (int mk = 1; mk < 16; mk <<= 1) {
#pragma unroll
          for (int jj = 0; jj < 5; jj++) p[jj] += __shfl_xor(p[jj], mk, 64);
        }
        if (lead) {                      // RNN2 + LN2 + pool, one lane per row
          float xn[5];
#pragma unroll
          for (int j = 0; j < 5; j++) {
            float a = p[j] + t2v[j];
#pragma unroll
            for (int jj = 0; jj < 5; jj++) a = fmaf(whh2v[j][jj], h2s[jj], a);
            xn[j] = tanh_fast(a);
          }
          float m2 = 0.f;
#pragma unroll
          for (int j = 0; j < 5; j++) m2 += xn[j];
          m2 *= 0.2f;
          float v2 = 0.f;
#pragma unroll
          for (int j = 0; j < 5; j++) { float d = xn[j] - m2; v2 += d * d; }
          v2 *= 0.2f;
          float r2 = rsqrtf(v2 + EPSL);
#pragma unroll
          for (int j = 0; j < 5; j++) {
            poolv[j] += (xn[j] - m2) * r2 * g2v[j] + be2v[j];
            h2s[j] = xn[j];
          }
        }
      }
      if (t < S_LEN - 1) {               // now convert + stage e[t+1]
        Frag8 pk;
#pragma unroll
        for (int j = 0; j < 8; j++) pk.us[j] = f2bf_bits(pf[j]);
        *(int4*)&e_bf[(t + 1) & 1][m * 128 + ((oct ^ m) & 15) * 8] = pk.i4;
      }
    }
    __syncthreads();   // the single per-step barrier (uniform flow)
  }

  if (!is_prod && lead) {
    float lg[5], mx = -1e30f;
#pragma unroll
    for (int j = 0; j < 5; j++) { lg[j] = poolv[j] * (1.f / 256.f); mx = fmaxf(mx, lg[j]); }
    float sm = 0.f, ex[5];
#pragma unroll
    for (int j = 0; j < 5; j++) { ex[j] = __expf(lg[j] - mx); sm += ex[j]; }
    float inv = 1.f / sm;
#pragma unroll
    for (int j = 0; j < 5; j++) out[(size_t)(r0 + myrow) * 5 + j] = ex[j] * inv;
  }
}

extern "C" void kernel_launch(void* const* d_in, const int* in_sizes, int n_in,
                              void* d_out, int out_size, void* d_ws, size_t ws_size,
                              hipStream_t stream) {
  (void)in_sizes; (void)n_in; (void)d_ws; (void)ws_size; (void)out_size;
  rnn_fused<<<dim3(64), dim3(512), 0, stream>>>(
      (const int*)  d_in[0],  (const float*)d_in[1],  (const float*)d_in[2],
      (const float*)d_in[3],  (const float*)d_in[4],  (const float*)d_in[5],
      (const float*)d_in[6],  (const float*)d_in[7],  (const float*)d_in[8],
      (const float*)d_in[9],  (const float*)d_in[10], (const float*)d_in[11],
      (const float*)d_in[12], (const float*)d_in[13], (float*)d_out);
}

// Round 3
// 355.106 us; speedup vs baseline: 1.8228x; 1.1449x over previous
//
#include <hip/hip_runtime.h>
#include <stdint.h>

#define S_LEN 256
#define DIM   128
#define EPSL  1e-5f

typedef __bf16 bf16x8 __attribute__((ext_vector_type(8)));
typedef float  f32x4  __attribute__((ext_vector_type(4)));

__device__ __forceinline__ unsigned short f2bf_bits(float f) {
  union { float f; unsigned int u; } v; v.f = f;
  unsigned int r = v.u + 0x7fffu + ((v.u >> 16) & 1u);   // RTNE
  return (unsigned short)(r >> 16);
}
__device__ __forceinline__ float bf2f_bits(unsigned short b) {
  union { float f; unsigned int u; } v; v.u = ((unsigned int)b) << 16; return v.f;
}
// tanh(x) = 1 - 2/(e^{2x}+1): v_exp + v_rcp, ~1e-6 rel err, exact at +-inf.
__device__ __forceinline__ float tanh_fast(float x) {
  float e = __expf(2.f * x);
  return 1.f - 2.f * __builtin_amdgcn_rcpf(e + 1.f);
}

// VALU cross-lane add via DPP rotation (replaces ds-pipe __shfl_xor chains).
// Full 16-lane sum on all lanes: levels row_ror:4, row_ror:8, quad rot1, rot2.
template<int CTRL>
__device__ __forceinline__ float dpp_rot_add(float v) {
  int r = __builtin_amdgcn_update_dpp(0, __float_as_int(v), CTRL, 0xF, 0xF, true);
  return v + __int_as_float(r);
}
template<int CTRL>
__device__ __forceinline__ void red_level7(float& s, float& sq, float* d) {
  s  = dpp_rot_add<CTRL>(s);
  sq = dpp_rot_add<CTRL>(sq);
#pragma unroll
  for (int j = 0; j < 5; j++) d[j] = dpp_rot_add<CTRL>(d[j]);
}

union Frag8 { unsigned short us[8]; bf16x8 v; int4 i4; };

// 8 waves: 0-3 recurrence (MFMA, W in VGPRs), 4-7 LN1/RNN2/LN2/pool + e-gather.
// One raw barrier per step (lgkmcnt-only drain: global prefetch stays in flight).
__global__ __launch_bounds__(512, 2)
void rnn_fused(const int* __restrict__ x,
               const float* __restrict__ emb,
               const float* __restrict__ Wih1,
               const float* __restrict__ bih1,
               const float* __restrict__ Whh1,
               const float* __restrict__ bhh1,
               const float* __restrict__ g1,
               const float* __restrict__ be1,
               const float* __restrict__ Wih2,
               const float* __restrict__ bih2,
               const float* __restrict__ Whh2,
               const float* __restrict__ bhh2,
               const float* __restrict__ g2,
               const float* __restrict__ be2,
               float* __restrict__ out)
{
  // element (row m, channel c) at m*128 + ((c>>3) ^ (m&15))*8 + (c&7)
  __shared__ __align__(16) unsigned short h_bf[2][16 * 128];   // 8 KB
  __shared__ __align__(16) unsigned short e_bf[2][16 * 128];   // 8 KB
  __shared__ int x_tile[16 * 256];                             // 16 KB

  const int tid  = threadIdx.x;
  const int wave = tid >> 6;
  const int lane = tid & 63;
  const int r0   = blockIdx.x * 16;
  const int l15  = lane & 15;
  const int q    = lane >> 4;

  for (int i = tid; i < 16 * 256; i += 512)
    x_tile[i] = x[(size_t)(r0 + (i >> 8)) * S_LEN + (i & 255)];
  for (int i = tid; i < 16 * 128; i += 512) h_bf[1][i] = 0;   // h_{-1} = 0

  const bool is_prod = (wave < 4);

  // ---- producer state ----
  bf16x8 wih[2][4], whi[2][4], wlo[2][4];
  float bias1v[2];
  // ---- consumer state ----
  float w2g[5][8];                     // (Wih2*g1) for this lane's 8 channels
  float Gs[5], Bs[5];                  // G_j = sum(W2*g1), B_j = sum(W2*be1)
  float whh2v[5][5], t2v[5], g2v[5], be2v[5], h2s[5], poolv[5];
  float pf[2][8];                      // e-prefetch double buffer (regs)
  int myrow = 0;
  bool lead = false;

  if (is_prod) {
    // B-frag: lane holds B[k = kt*32 + q*8 + j][n = nt*16 + l15] = W[n][k]
#pragma unroll
    for (int ntL = 0; ntL < 2; ntL++) {
      int n = (wave * 2 + ntL) * 16 + l15;
      bias1v[ntL] = bih1[n] + bhh1[n];
#pragma unroll
      for (int kt = 0; kt < 4; kt++) {
        int k0 = kt * 32 + q * 8;
        Frag8 fa, fh, fl;
#pragma unroll
        for (int j = 0; j < 8; j++) {
          fa.us[j] = f2bf_bits(Wih1[n * DIM + k0 + j]);
          float w = Whh1[n * DIM + k0 + j];
          unsigned short hi = f2bf_bits(w);
          fh.us[j] = hi;
          fl.us[j] = f2bf_bits(w - bf2f_bits(hi));   // split-bf16 compensation
        }
        wih[ntL][kt] = fa.v; whi[ntL][kt] = fh.v; wlo[ntL][kt] = fl.v;
      }
    }
  } else {
    myrow = (wave - 4) * 4 + q;        // 16 lanes per row
    lead  = (l15 == 0);
    int coct = (l15 ^ myrow) & 15;     // storage oct l15 -> channels coct*8..+7
#pragma unroll
    for (int j = 0; j < 8; j++) {
      int c = coct * 8 + j;
      float gc = g1[c];
#pragma unroll
      for (int jj = 0; jj < 5; jj++) w2g[jj][j] = Wih2[jj * DIM + c] * gc;
    }
#pragma unroll
    for (int jj = 0; jj < 5; jj++) { Gs[jj] = 0.f; Bs[jj] = 0.f; }
    for (int c = 0; c < DIM; c++) {    // init-only: small scalar loop
      float gc = g1[c], bc = be1[c];
#pragma unroll
      for (int jj = 0; jj < 5; jj++) {
        float w = Wih2[jj * DIM + c];
        Gs[jj] += w * gc; Bs[jj] += w * bc;
      }
    }
#pragma unroll
    for (int j = 0; j < 5; j++) {
      t2v[j] = bih2[j] + bhh2[j];
      g2v[j] = g2[j]; be2v[j] = be2[j];
      h2s[j] = 0.f; poolv[j] = 0.f;
#pragma unroll
      for (int jj = 0; jj < 5; jj++) whh2v[j][jj] = Whh2[j * 5 + jj];
    }
  }

  __syncthreads();

  if (!is_prod) {                      // stage e[0]; preload pf[1] <- e[1]
    int ti2 = tid - 256;
    int m = ti2 >> 4, oct = ti2 & 15;
    {
      int xid = x_tile[m * 256];
      const float* pe = emb + (size_t)xid * DIM + oct * 8;
      Frag8 pk;
#pragma unroll
      for (int j = 0; j < 8; j++) pk.us[j] = f2bf_bits(pe[j]);
      *(int4*)&e_bf[0][m * 128 + ((oct ^ m) & 15) * 8] = pk.i4;
    }
    {
      int xid = x_tile[m * 256 + 1];
      const float* pe = emb + (size_t)xid * DIM + oct * 8;
#pragma unroll
      for (int j = 0; j < 8; j++) pf[1][j] = pe[j];
    }
  }
  __syncthreads();

#pragma unroll 2                       // makes t&1 static: pf[] stays in regs
  for (int t = 0; t <= S_LEN; t++) {
    if (is_prod) {
      if (t < S_LEN) {
        const int rb = (t + 1) & 1;    // h_{t-1}
        const int eb = t & 1;          // e_t
        f32x4 ac_e[2], ac_h[2], ac_l[2];
#pragma unroll
        for (int u = 0; u < 2; u++) {
          ac_e[u] = f32x4{0.f, 0.f, 0.f, 0.f};
          ac_h[u] = f32x4{0.f, 0.f, 0.f, 0.f};
          ac_l[u] = f32x4{0.f, 0.f, 0.f, 0.f};
        }
#pragma unroll
        for (int kt = 0; kt < 4; kt++) {
          int sw = (((kt * 4 + q) ^ l15) & 15) * 8;
          bf16x8 ae = *(const bf16x8*)&e_bf[eb][l15 * 128 + sw];
          bf16x8 ah = *(const bf16x8*)&h_bf[rb][l15 * 128 + sw];
          ac_e[0] = __builtin_amdgcn_mfma_f32_16x16x32_bf16(ae, wih[0][kt], ac_e[0], 0, 0, 0);
          ac_e[1] = __builtin_amdgcn_mfma_f32_16x16x32_bf16(ae, wih[1][kt], ac_e[1], 0, 0, 0);
          ac_h[0] = __builtin_amdgcn_mfma_f32_16x16x32_bf16(ah, whi[0][kt], ac_h[0], 0, 0, 0);
          ac_h[1] = __builtin_amdgcn_mfma_f32_16x16x32_bf16(ah, whi[1][kt], ac_h[1], 0, 0, 0);
          ac_l[0] = __builtin_amdgcn_mfma_f32_16x16x32_bf16(ah, wlo[0][kt], ac_l[0], 0, 0, 0);
          ac_l[1] = __builtin_amdgcn_mfma_f32_16x16x32_bf16(ah, wlo[1][kt], ac_l[1], 0, 0, 0);
        }
        const int wb = t & 1;          // h_t
#pragma unroll
        for (int ntL = 0; ntL < 2; ntL++) {
          int c = (wave * 2 + ntL) * 16 + l15;
          int oct = c >> 3;
#pragma unroll
          for (int r = 0; r < 4; r++) {  // D-layout: row = q*4 + r, col = l15
            int row = q * 4 + r;
            float av = (ac_e[ntL][r] + ac_h[ntL][r]) + (ac_l[ntL][r] + bias1v[ntL]);
            h_bf[wb][row * 128 + ((oct ^ row) & 15) * 8 + (c & 7)] = f2bf_bits(tanh_fast(av));
          }
        }
      }
    } else {
      const int ti2 = tid - 256;
      const int m   = ti2 >> 4;
      const int oct = ti2 & 15;
      if (t + 2 < S_LEN) {             // issue loads for e[t+2] (land at t+1)
        int xid = x_tile[m * 256 + t + 2];
        const float* pe = emb + (size_t)xid * DIM + oct * 8;
#pragma unroll
        for (int j = 0; j < 8; j++) pf[t & 1][j] = pe[j];
      }
      if (t + 1 < S_LEN) {             // write e[t+1] from pf loaded at t-1
        Frag8 pk;
#pragma unroll
        for (int j = 0; j < 8; j++) pk.us[j] = f2bf_bits(pf[(t & 1) ^ 1][j]);
        *(int4*)&e_bf[(t + 1) & 1][m * 128 + ((oct ^ m) & 15) * 8] = pk.i4;
      }
      if (t >= 1) {                    // LN1 -> proj -> RNN2 -> LN2 -> pool
        const int hb = (t - 1) & 1;
        Frag8 hr;
        hr.i4 = *(const int4*)&h_bf[hb][myrow * 128 + l15 * 8];
        float s = 0.f, sq = 0.f, d[5] = {0, 0, 0, 0, 0};
#pragma unroll
        for (int j = 0; j < 8; j++) {
          float v = bf2f_bits(hr.us[j]);
          s += v; sq += v * v;
#pragma unroll
          for (int jj = 0; jj < 5; jj++) d[jj] = fmaf(w2g[jj][j], v, d[jj]);
        }
        // one 4-level DPP butterfly for all 7 partials (VALU, no LDS pipe)
        red_level7<0x124>(s, sq, d);   // row_ror:4
        red_level7<0x128>(s, sq, d);   // row_ror:8
        red_level7<0x39>(s, sq, d);    // quad rot 1
        red_level7<0x4E>(s, sq, d);    // quad rot 2
        if (lead) {
          float mean = s * (1.f / 128.f);
          float var  = sq * (1.f / 128.f) - mean * mean;
          float rstd = rsqrtf(var + EPSL);
          float xn[5];
#pragma unroll
          for (int j = 0; j < 5; j++) {
            // p_j = rstd*(D_j - mean*G_j) + B_j   (exact fold of LN1+proj)
            float a = rstd * (d[j] - mean * Gs[j]) + Bs[j] + t2v[j];
#pragma unroll
            for (int jj = 0; jj < 5; jj++) a = fmaf(whh2v[j][jj], h2s[jj], a);
            xn[j] = tanh_fast(a);
          }
          float m2 = 0.f;
#pragma unroll
          for (int j = 0; j < 5; j++) m2 += xn[j];
          m2 *= 0.2f;
          float v2 = 0.f;
#pragma unroll
          for (int j = 0; j < 5; j++) { float dd = xn[j] - m2; v2 += dd * dd; }
          v2 *= 0.2f;
          float r2 = rsqrtf(v2 + EPSL);
#pragma unroll
          for (int j = 0; j < 5; j++) {
            poolv[j] += (xn[j] - m2) * r2 * g2v[j] + be2v[j];
            h2s[j] = xn[j];
          }
        }
      }
    }
    // Raw barrier: drain LDS only; global prefetch loads stay in flight.
    asm volatile("s_waitcnt lgkmcnt(0)\n\ts_barrier" ::: "memory");
  }

  if (!is_prod && lead) {
    float lg[5], mx = -1e30f;
#pragma unroll
    for (int j = 0; j < 5; j++) { lg[j] = poolv[j] * (1.f / 256.f); mx = fmaxf(mx, lg[j]); }
    float sm = 0.f, ex[5];
#pragma unroll
    for (int j = 0; j < 5; j++) { ex[j] = __expf(lg[j] - mx); sm += ex[j]; }
    float inv = 1.f / sm;
#pragma unroll
    for (int j = 0; j < 5; j++) out[(size_t)(r0 + myrow) * 5 + j] = ex[j] * inv;
  }
}

extern "C" void kernel_launch(void* const* d_in, const int* in_sizes, int n_in,
                              void* d_out, int out_size, void* d_ws, size_t ws_size,
                              hipStream_t stream) {
  (void)in_sizes; (void)n_in; (void)d_ws; (void)ws_size; (void)out_size;
  rnn_fused<<<dim3(64), dim3(512), 0, stream>>>(
      (const int*)  d_in[0],  (const float*)d_in[1],  (const float*)d_in[2],
      (const float*)d_in[3],  (const float*)d_in[4],  (const float*)d_in[5],
      (const float*)d_in[6],  (const float*)d_in[7],  (const float*)d_in[8],
      (const float*)d_in[9],  (const float*)d_in[10], (const float*)d_in[11],
      (const float*)d_in[12], (const float*)d_in[13], (float*)d_out);
}

// Round 4
// 334.059 us; speedup vs baseline: 1.9376x; 1.0630x over previous
//
#include <hip/hip_runtime.h>
#include <stdint.h>

#define S_LEN 256
#define DIM   128
#define EPSL  1e-5f

typedef __bf16 bf16x8 __attribute__((ext_vector_type(8)));
typedef float  f32x4  __attribute__((ext_vector_type(4)));

__device__ __forceinline__ unsigned short f2bf_bits(float f) {
  union { float f; unsigned int u; } v; v.f = f;
  unsigned int r = v.u + 0x7fffu + ((v.u >> 16) & 1u);   // RTNE
  return (unsigned short)(r >> 16);
}
__device__ __forceinline__ float bf2f_bits(unsigned short b) {
  union { float f; unsigned int u; } v; v.u = ((unsigned int)b) << 16; return v.f;
}
// tanh(x) = 1 - 2/(e^{2x}+1): v_exp + v_rcp, ~1e-6 rel err, exact at +-inf.
__device__ __forceinline__ float tanh_fast(float x) {
  float e = __expf(2.f * x);
  return 1.f - 2.f * __builtin_amdgcn_rcpf(e + 1.f);
}

// VALU cross-lane add via DPP rotation; full 16-lane sum on all lanes.
template<int CTRL>
__device__ __forceinline__ float dpp_rot_add(float v) {
  int r = __builtin_amdgcn_update_dpp(0, __float_as_int(v), CTRL, 0xF, 0xF, true);
  return v + __int_as_float(r);
}
template<int CTRL>
__device__ __forceinline__ void red_level7(float& s, float& sq, float* d) {
  s  = dpp_rot_add<CTRL>(s);
  sq = dpp_rot_add<CTRL>(sq);
#pragma unroll
  for (int j = 0; j < 5; j++) d[j] = dpp_rot_add<CTRL>(d[j]);
}

union Frag8 { unsigned short us[8]; bf16x8 v; int4 i4; };

// 8 waves. Producers (0-3): ONLY the serial part h@Whh (16 MFMA) + tanh.
// Consumers (4-7): e-gather, e@Wih MFMA one step ahead (their MFMA pipe was
// idle), xp handoff ring, LN1/proj/RNN2/LN2/pool. One raw barrier per step.
__global__ __launch_bounds__(512, 2)
void rnn_fused(const int* __restrict__ x,
               const float* __restrict__ emb,
               const float* __restrict__ Wih1,
               const float* __restrict__ bih1,
               const float* __restrict__ Whh1,
               const float* __restrict__ bhh1,
               const float* __restrict__ g1,
               const float* __restrict__ be1,
               const float* __restrict__ Wih2,
               const float* __restrict__ bih2,
               const float* __restrict__ Whh2,
               const float* __restrict__ bhh2,
               const float* __restrict__ g2,
               const float* __restrict__ be2,
               float* __restrict__ out)
{
  // h/e element (row m, channel c) at m*128 + ((c>>3) ^ (m&15))*8 + (c&7)
  __shared__ __align__(16) unsigned short h_bf[2][16 * 128];   // 8 KB
  __shared__ __align__(16) unsigned short e_bf[2][16 * 128];   // 8 KB
  __shared__ __align__(16) float          xp[2][256 * 8];      // 16 KB handoff
  __shared__ int x_tile[16 * 256];                             // 16 KB

  const int tid  = threadIdx.x;
  const int wave = tid >> 6;
  const int lane = tid & 63;
  const int r0   = blockIdx.x * 16;
  const int l15  = lane & 15;
  const int q    = lane >> 4;

  for (int i = tid; i < 16 * 256; i += 512)
    x_tile[i] = x[(size_t)(r0 + (i >> 8)) * S_LEN + (i & 255)];
  for (int i = tid; i < 16 * 128; i += 512) h_bf[1][i] = 0;   // h_{-1} = 0

  const bool is_prod = (wave < 4);

  // ---- producer state: Whh split-bf16 frags only ----
  bf16x8 whi[2][4], wlo[2][4];
  // ---- consumer state ----
  bf16x8 wih[2][4];                    // B-frags for e@Wih^T (this wave's n)
  float bias1v2[2];
  float w2g[5][8], Gs[5], Bs[5];
  float whh2v[5][5], t2v[5], g2v[5], be2v[5], h2s[5], poolv[5];
  float pf[2][8];                      // e-gather double buffer (2-step cover)
  int myrow = 0;
  bool lead = false;

  if (is_prod) {
    // B-frag: lane holds B[k = kt*32 + q*8 + j][n = wave*32 + ntL*16 + l15]
#pragma unroll
    for (int ntL = 0; ntL < 2; ntL++) {
      int n = wave * 32 + ntL * 16 + l15;
#pragma unroll
      for (int kt = 0; kt < 4; kt++) {
        int k0 = kt * 32 + q * 8;
        Frag8 fh, fl;
#pragma unroll
        for (int j = 0; j < 8; j++) {
          float w = Whh1[n * DIM + k0 + j];
          unsigned short hi = f2bf_bits(w);
          fh.us[j] = hi;
          fl.us[j] = f2bf_bits(w - bf2f_bits(hi));   // split-bf16 compensation
        }
        whi[ntL][kt] = fh.v; wlo[ntL][kt] = fl.v;
      }
    }
  } else {
    const int cw = wave - 4;
#pragma unroll
    for (int ntL = 0; ntL < 2; ntL++) {
      int n = cw * 32 + ntL * 16 + l15;
      bias1v2[ntL] = bih1[n] + bhh1[n];
#pragma unroll
      for (int kt = 0; kt < 4; kt++) {
        int k0 = kt * 32 + q * 8;
        Frag8 fa;
#pragma unroll
        for (int j = 0; j < 8; j++) fa.us[j] = f2bf_bits(Wih1[n * DIM + k0 + j]);
        wih[ntL][kt] = fa.v;
      }
    }
    myrow = cw * 4 + q;                // LN role: 16 lanes per row
    lead  = (l15 == 0);
    int coct = (l15 ^ myrow) & 15;     // storage oct l15 -> channels coct*8..+7
#pragma unroll
    for (int j = 0; j < 8; j++) {
      int c = coct * 8 + j;
      float gc = g1[c];
#pragma unroll
      for (int jj = 0; jj < 5; jj++) w2g[jj][j] = Wih2[jj * DIM + c] * gc;
    }
#pragma unroll
    for (int jj = 0; jj < 5; jj++) { Gs[jj] = 0.f; Bs[jj] = 0.f; }
    for (int c = 0; c < DIM; c++) {    // init-only scalar loop
      float gc = g1[c], bc = be1[c];
#pragma unroll
      for (int jj = 0; jj < 5; jj++) {
        float w = Wih2[jj * DIM + c];
        Gs[jj] += w * gc; Bs[jj] += w * bc;
      }
    }
#pragma unroll
    for (int j = 0; j < 5; j++) {
      t2v[j] = bih2[j] + bhh2[j];
      g2v[j] = g2[j]; be2v[j] = be2[j];
      h2s[j] = 0.f; poolv[j] = 0.f;
#pragma unroll
      for (int jj = 0; jj < 5; jj++) whh2v[j][jj] = Whh2[j * 5 + jj];
    }
  }

  __syncthreads();

  // Prologue: stage e[0],e[1] into e_bf; preload pf[0]=e[2], pf[1]=e[3].
  if (!is_prod) {
    int ti2 = tid - 256;
    int m = ti2 >> 4, oct = ti2 & 15;
    const int dst = m * 128 + ((oct ^ m) & 15) * 8;
    float ta[8], tb[8];
    {
      int xid = x_tile[m * 256 + 0];
      const float* pe = emb + (size_t)xid * DIM + oct * 8;
#pragma unroll
      for (int j = 0; j < 8; j++) ta[j] = pe[j];
    }
    {
      int xid = x_tile[m * 256 + 1];
      const float* pe = emb + (size_t)xid * DIM + oct * 8;
#pragma unroll
      for (int j = 0; j < 8; j++) tb[j] = pe[j];
    }
    {
      int xid = x_tile[m * 256 + 2];
      const float* pe = emb + (size_t)xid * DIM + oct * 8;
#pragma unroll
      for (int j = 0; j < 8; j++) pf[0][j] = pe[j];
    }
    {
      int xid = x_tile[m * 256 + 3];
      const float* pe = emb + (size_t)xid * DIM + oct * 8;
#pragma unroll
      for (int j = 0; j < 8; j++) pf[1][j] = pe[j];
    }
    Frag8 pa, pb;
#pragma unroll
    for (int j = 0; j < 8; j++) { pa.us[j] = f2bf_bits(ta[j]); pb.us[j] = f2bf_bits(tb[j]); }
    *(int4*)&e_bf[0][dst] = pa.i4;
    *(int4*)&e_bf[1][dst] = pb.i4;
  }
  __syncthreads();

  if (!is_prod) {                      // xp[0] = e[0]@Wih^T + bias
    const int cw = wave - 4;
    f32x4 a0 = {0, 0, 0, 0}, a1 = {0, 0, 0, 0};
#pragma unroll
    for (int kt = 0; kt < 4; kt++) {
      int sw = (((kt * 4 + q) ^ l15) & 15) * 8;
      bf16x8 ae = *(const bf16x8*)&e_bf[0][l15 * 128 + sw];
      a0 = __builtin_amdgcn_mfma_f32_16x16x32_bf16(ae, wih[0][kt], a0, 0, 0, 0);
      a1 = __builtin_amdgcn_mfma_f32_16x16x32_bf16(ae, wih[1][kt], a1, 0, 0, 0);
    }
#pragma unroll
    for (int r = 0; r < 4; r++) { a0[r] += bias1v2[0]; a1[r] += bias1v2[1]; }
    *(f32x4*)&xp[0][(cw * 64 + lane) * 8]     = a0;
    *(f32x4*)&xp[0][(cw * 64 + lane) * 8 + 4] = a1;
  }
  __syncthreads();

#pragma unroll 2                       // static parities: pf[] stays in regs
  for (int t = 0; t <= S_LEN; t++) {
    if (is_prod) {
      if (t < S_LEN) {
        const int rb = (t + 1) & 1;    // h_{t-1}
        f32x4 ah0 = {0,0,0,0}, ah1 = {0,0,0,0}, al0 = {0,0,0,0}, al1 = {0,0,0,0};
#pragma unroll
        for (int kt = 0; kt < 4; kt++) {
          int sw = (((kt * 4 + q) ^ l15) & 15) * 8;
          bf16x8 ah = *(const bf16x8*)&h_bf[rb][l15 * 128 + sw];
          ah0 = __builtin_amdgcn_mfma_f32_16x16x32_bf16(ah, whi[0][kt], ah0, 0, 0, 0);
          ah1 = __builtin_amdgcn_mfma_f32_16x16x32_bf16(ah, whi[1][kt], ah1, 0, 0, 0);
          al0 = __builtin_amdgcn_mfma_f32_16x16x32_bf16(ah, wlo[0][kt], al0, 0, 0, 0);
          al1 = __builtin_amdgcn_mfma_f32_16x16x32_bf16(ah, wlo[1][kt], al1, 0, 0, 0);
        }
        const int pt = wave * 64 + lane;
        f32x4 xv0 = *(const f32x4*)&xp[t & 1][pt * 8];
        f32x4 xv1 = *(const f32x4*)&xp[t & 1][pt * 8 + 4];
        const int wb = t & 1;          // h_t
#pragma unroll
        for (int ntL = 0; ntL < 2; ntL++) {
          int c = wave * 32 + ntL * 16 + l15;
          int oct = c >> 3;
#pragma unroll
          for (int r = 0; r < 4; r++) {  // D-layout: row = q*4 + r, col = l15
            int row = q * 4 + r;
            float av = ntL ? (ah1[r] + al1[r] + xv1[r]) : (ah0[r] + al0[r] + xv0[r]);
            h_bf[wb][row * 128 + ((oct ^ row) & 15) * 8 + (c & 7)] = f2bf_bits(tanh_fast(av));
          }
        }
      }
    } else {
      const int ti2 = tid - 256;
      const int m   = ti2 >> 4;
      const int oct = ti2 & 15;
      const int cw  = wave - 4;
      if (t + 2 < S_LEN) {             // stage e[t+2] (gathered at t-2)
        Frag8 pk;
#pragma unroll
        for (int j = 0; j < 8; j++) pk.us[j] = f2bf_bits(pf[t & 1][j]);
        *(int4*)&e_bf[t & 1][m * 128 + ((oct ^ m) & 15) * 8] = pk.i4;
      }
      if (t + 4 < S_LEN) {             // issue gather e[t+4] (2-step cover)
        int xid = x_tile[m * 256 + t + 4];
        const float* pe = emb + (size_t)xid * DIM + oct * 8;
#pragma unroll
        for (int j = 0; j < 8; j++) pf[t & 1][j] = pe[j];
      }
      if (t + 1 < S_LEN) {             // xp[t+1] = e[t+1]@Wih^T + bias
        f32x4 a0 = {0, 0, 0, 0}, a1 = {0, 0, 0, 0};
#pragma unroll
        for (int kt = 0; kt < 4; kt++) {
          int sw = (((kt * 4 + q) ^ l15) & 15) * 8;
          bf16x8 ae = *(const bf16x8*)&e_bf[(t + 1) & 1][l15 * 128 + sw];
          a0 = __builtin_amdgcn_mfma_f32_16x16x32_bf16(ae, wih[0][kt], a0, 0, 0, 0);
          a1 = __builtin_amdgcn_mfma_f32_16x16x32_bf16(ae, wih[1][kt], a1, 0, 0, 0);
        }
#pragma unroll
        for (int r = 0; r < 4; r++) { a0[r] += bias1v2[0]; a1[r] += bias1v2[1]; }
        *(f32x4*)&xp[(t + 1) & 1][(cw * 64 + lane) * 8]     = a0;
        *(f32x4*)&xp[(t + 1) & 1][(cw * 64 + lane) * 8 + 4] = a1;
      }
      if (t >= 1) {                    // LN1 -> proj -> RNN2 -> LN2 -> pool
        const int hb = (t - 1) & 1;
        Frag8 hr;
        hr.i4 = *(const int4*)&h_bf[hb][myrow * 128 + l15 * 8];
        float s = 0.f, sq = 0.f, d[5] = {0, 0, 0, 0, 0};
#pragma unroll
        for (int j = 0; j < 8; j++) {
          float v = bf2f_bits(hr.us[j]);
          s += v; sq += v * v;
#pragma unroll
          for (int jj = 0; jj < 5; jj++) d[jj] = fmaf(w2g[jj][j], v, d[jj]);
        }
        red_level7<0x124>(s, sq, d);   // row_ror:4
        red_level7<0x128>(s, sq, d);   // row_ror:8
        red_level7<0x39>(s, sq, d);    // quad rot 1
        red_level7<0x4E>(s, sq, d);    // quad rot 2
        if (lead) {
          float mean = s * (1.f / 128.f);
          float var  = sq * (1.f / 128.f) - mean * mean;
          float rstd = rsqrtf(var + EPSL);
          float xn[5];
#pragma unroll
          for (int j = 0; j < 5; j++) {
            float a = rstd * (d[j] - mean * Gs[j]) + Bs[j] + t2v[j];
#pragma unroll
            for (int jj = 0; jj < 5; jj++) a = fmaf(whh2v[j][jj], h2s[jj], a);
            xn[j] = tanh_fast(a);
          }
          float m2 = 0.f;
#pragma unroll
          for (int j = 0; j < 5; j++) m2 += xn[j];
          m2 *= 0.2f;
          float v2 = 0.f;
#pragma unroll
          for (int j = 0; j < 5; j++) { float dd = xn[j] - m2; v2 += dd * dd; }
          v2 *= 0.2f;
          float r2 = rsqrtf(v2 + EPSL);
#pragma unroll
          for (int j = 0; j < 5; j++) {
            poolv[j] += (xn[j] - m2) * r2 * g2v[j] + be2v[j];
            h2s[j] = xn[j];
          }
        }
      }
    }
    // Raw barrier: drain LDS only; global gather loads stay in flight.
    asm volatile("s_waitcnt lgkmcnt(0)\n\ts_barrier" ::: "memory");
  }

  if (!is_prod && lead) {
    float lg[5], mx = -1e30f;
#pragma unroll
    for (int j = 0; j < 5; j++) { lg[j] = poolv[j] * (1.f / 256.f); mx = fmaxf(mx, lg[j]); }
    float sm = 0.f, ex[5];
#pragma unroll
    for (int j = 0; j < 5; j++) { ex[j] = __expf(lg[j] - mx); sm += ex[j]; }
    float inv = 1.f / sm;
#pragma unroll
    for (int j = 0; j < 5; j++) out[(size_t)(r0 + myrow) * 5 + j] = ex[j] * inv;
  }
}

extern "C" void kernel_launch(void* const* d_in, const int* in_sizes, int n_in,
                              void* d_out, int out_size, void* d_ws, size_t ws_size,
                              hipStream_t stream) {
  (void)in_sizes; (void)n_in; (void)d_ws; (void)ws_size; (void)out_size;
  rnn_fused<<<dim3(64), dim3(512), 0, stream>>>(
      (const int*)  d_in[0],  (const float*)d_in[1],  (const float*)d_in[2],
      (const float*)d_in[3],  (const float*)d_in[4],  (const float*)d_in[5],
      (const float*)d_in[6],  (const float*)d_in[7],  (const float*)d_in[8],
      (const float*)d_in[9],  (const float*)d_in[10], (const float*)d_in[11],
      (const float*)d_in[12], (const float*)d_in[13], (float*)d_out);
}

// Round 5
// 325.048 us; speedup vs baseline: 1.9913x; 1.0277x over previous
//
#include <hip/hip_runtime.h>
#include <stdint.h>

#define S_LEN 256
#define DIM   128
#define EPSL  1e-5f

typedef __bf16 bf16x8 __attribute__((ext_vector_type(8)));
typedef float  f32x4  __attribute__((ext_vector_type(4)));

__device__ __forceinline__ unsigned short f2bf_bits(float f) {
  union { float f; unsigned int u; } v; v.f = f;
  unsigned int r = v.u + 0x7fffu + ((v.u >> 16) & 1u);   // RTNE (init paths)
  return (unsigned short)(r >> 16);
}
__device__ __forceinline__ float bf2f_bits(unsigned short b) {
  union { float f; unsigned int u; } v; v.u = ((unsigned int)b) << 16; return v.f;
}
// Hot-path bf16: round-half-up (+0x8000 >> 16): 2 VALU ops vs ~4 for RTNE.
__device__ __forceinline__ unsigned f2bf_rhu(float f) {
  return (__float_as_uint(f) + 0x8000u) >> 16;
}
// Pack two floats -> (bf16 lo, bf16 hi) in one u32: 2 adds + 1 v_perm.
__device__ __forceinline__ unsigned pack_rhu(float lo, float hi) {
  return __builtin_amdgcn_perm(__float_as_uint(hi) + 0x8000u,
                               __float_as_uint(lo) + 0x8000u, 0x07060302u);
}
// tanh(x) = 1 - 2/(e^{2x}+1): ~1e-6 rel err, exact at +-inf.
__device__ __forceinline__ float tanh_fast(float x) {
  float e = __expf(2.f * x);
  return 1.f - 2.f * __builtin_amdgcn_rcpf(e + 1.f);
}

// VALU cross-lane ops via DPP rotation; full 16-lane reduce on all lanes.
template<int CTRL>
__device__ __forceinline__ float dpp_rot_add(float v) {
  int r = __builtin_amdgcn_update_dpp(0, __float_as_int(v), CTRL, 0xF, 0xF, true);
  return v + __int_as_float(r);
}
template<int CTRL>
__device__ __forceinline__ float dpp_rot_max(float v) {
  int r = __builtin_amdgcn_update_dpp(0, __float_as_int(v), CTRL, 0xF, 0xF, true);
  return fmaxf(v, __int_as_float(r));
}
__device__ __forceinline__ float dpp_sum16(float v) {
  v = dpp_rot_add<0x124>(v); v = dpp_rot_add<0x128>(v);
  v = dpp_rot_add<0x39>(v);  v = dpp_rot_add<0x4E>(v);
  return v;
}
__device__ __forceinline__ float dpp_max16(float v) {
  v = dpp_rot_max<0x124>(v); v = dpp_rot_max<0x128>(v);
  v = dpp_rot_max<0x39>(v);  v = dpp_rot_max<0x4E>(v);
  return v;
}
template<int CTRL>
__device__ __forceinline__ void red_level7(float& s, float& sq, float* d) {
  s  = dpp_rot_add<CTRL>(s);
  sq = dpp_rot_add<CTRL>(sq);
#pragma unroll
  for (int j = 0; j < 5; j++) d[j] = dpp_rot_add<CTRL>(d[j]);
}
// Broadcast lane (q*16 + jj)'s value to all lanes of its 16-group.
template<int JJ>
__device__ __forceinline__ float bcast16(float v) {
  int r = __builtin_amdgcn_ds_swizzle(__float_as_int(v), (JJ << 5) | 0x10);
  return __int_as_float(r);
}

union Frag8 { unsigned short us[8]; bf16x8 v; int4 i4; };

// 8 waves. Producers (0-3): serial h@Whh (16 MFMA, lo-chain seeded with xp)
// + tanh + h write. Consumers (4-7): e-gather, e@Wih one step ahead (bias in
// acc init), LN1 fold, RNN2/LN2/pool spread over 16 lanes (1 tanh issue, DPP
// reduces, ds_swizzle h2 broadcast). One raw lgkm-only barrier per step.
__global__ __launch_bounds__(512, 2)
void rnn_fused(const int* __restrict__ x,
               const float* __restrict__ emb,
               const float* __restrict__ Wih1,
               const float* __restrict__ bih1,
               const float* __restrict__ Whh1,
               const float* __restrict__ bhh1,
               const float* __restrict__ g1,
               const float* __restrict__ be1,
               const float* __restrict__ Wih2,
               const float* __restrict__ bih2,
               const float* __restrict__ Whh2,
               const float* __restrict__ bhh2,
               const float* __restrict__ g2,
               const float* __restrict__ be2,
               float* __restrict__ out)
{
  // h/e element (row m, channel c) at m*128 + ((c>>3) ^ (m&15))*8 + (c&7)
  __shared__ __align__(16) unsigned short h_bf[2][16 * 128];   // 8 KB
  __shared__ __align__(16) unsigned short e_bf[2][16 * 128];   // 8 KB
  __shared__ __align__(16) float          xp[2][256 * 8];      // 16 KB handoff
  __shared__ int x_tile[16 * 256];                             // 16 KB

  const int tid  = threadIdx.x;
  const int wave = tid >> 6;
  const int lane = tid & 63;
  const int r0   = blockIdx.x * 16;
  const int l15  = lane & 15;
  const int q    = lane >> 4;

  for (int i = tid; i < 16 * 256; i += 512)
    x_tile[i] = x[(size_t)(r0 + (i >> 8)) * S_LEN + (i & 255)];
  for (int i = tid; i < 16 * 128; i += 512) h_bf[1][i] = 0;   // h_{-1} = 0

  const bool is_prod = (wave < 4);

  // ---- producer state: Whh split-bf16 frags only ----
  bf16x8 whi[2][4], wlo[2][4];
  // ---- consumer state ----
  bf16x8 wih[2][4];
  float bias1v2[2];
  float w2g[5][8], Gs[5], Bs[5];
  float wrow[5];                        // per-lane row l15 of Whh2 (0 if l15>=5)
  float t2_l = 0.f, g2_l = 0.f, be2_l = 0.f, validf = 0.f;
  float h2rep[5];                       // h2 state replicated in all lanes
  float pool_l = 0.f;                   // lane l15<5 holds pool[l15] for myrow
  float pf[2][8];                       // e-gather double buffer (2-step cover)
  int myrow = 0;

  if (is_prod) {
    // B-frag: lane holds B[k = kt*32 + q*8 + j][n = wave*32 + ntL*16 + l15]
#pragma unroll
    for (int ntL = 0; ntL < 2; ntL++) {
      int n = wave * 32 + ntL * 16 + l15;
#pragma unroll
      for (int kt = 0; kt < 4; kt++) {
        int k0 = kt * 32 + q * 8;
        Frag8 fh, fl;
#pragma unroll
        for (int j = 0; j < 8; j++) {
          float w = Whh1[n * DIM + k0 + j];
          unsigned short hi = f2bf_bits(w);
          fh.us[j] = hi;
          fl.us[j] = f2bf_bits(w - bf2f_bits(hi));   // split-bf16 compensation
        }
        whi[ntL][kt] = fh.v; wlo[ntL][kt] = fl.v;
      }
    }
  } else {
    const int cw = wave - 4;
#pragma unroll
    for (int ntL = 0; ntL < 2; ntL++) {
      int n = cw * 32 + ntL * 16 + l15;
      bias1v2[ntL] = bih1[n] + bhh1[n];
#pragma unroll
      for (int kt = 0; kt < 4; kt++) {
        int k0 = kt * 32 + q * 8;
        Frag8 fa;
#pragma unroll
        for (int j = 0; j < 8; j++) fa.us[j] = f2bf_bits(Wih1[n * DIM + k0 + j]);
        wih[ntL][kt] = fa.v;
      }
    }
    myrow = cw * 4 + q;
    int coct = (l15 ^ myrow) & 15;     // storage oct l15 -> channels coct*8..+7
#pragma unroll
    for (int j = 0; j < 8; j++) {
      int c = coct * 8 + j;
      float gc = g1[c];
#pragma unroll
      for (int jj = 0; jj < 5; jj++) w2g[jj][j] = Wih2[jj * DIM + c] * gc;
    }
#pragma unroll
    for (int jj = 0; jj < 5; jj++) { Gs[jj] = 0.f; Bs[jj] = 0.f; }
    for (int c = 0; c < DIM; c++) {    // init-only scalar loop
      float gc = g1[c], bc = be1[c];
#pragma unroll
      for (int jj = 0; jj < 5; jj++) {
        float w = Wih2[jj * DIM + c];
        Gs[jj] += w * gc; Bs[jj] += w * bc;
      }
    }
    // per-lane RNN2/LN2 role: lane l15 owns hidden dim l15 (l15<5)
    validf = (l15 < 5) ? 1.f : 0.f;
    if (l15 < 5) {
      t2_l = bih2[l15] + bhh2[l15];
      g2_l = g2[l15]; be2_l = be2[l15];
#pragma unroll
      for (int jj = 0; jj < 5; jj++) wrow[jj] = Whh2[l15 * 5 + jj];
    } else {
#pragma unroll
      for (int jj = 0; jj < 5; jj++) wrow[jj] = 0.f;
    }
#pragma unroll
    for (int jj = 0; jj < 5; jj++) h2rep[jj] = 0.f;
  }

  __syncthreads();

  // Prologue: stage e[0],e[1] into e_bf; preload pf[0]=e[2], pf[1]=e[3].
  if (!is_prod) {
    int ti2 = tid - 256;
    int m = ti2 >> 4, oct = ti2 & 15;
    const int dst = m * 128 + ((oct ^ m) & 15) * 8;
    float ta[8], tb[8];
    {
      int xid = x_tile[m * 256 + 0];
      const float* pe = emb + (size_t)xid * DIM + oct * 8;
#pragma unroll
      for (int j = 0; j < 8; j++) ta[j] = pe[j];
    }
    {
      int xid = x_tile[m * 256 + 1];
      const float* pe = emb + (size_t)xid * DIM + oct * 8;
#pragma unroll
      for (int j = 0; j < 8; j++) tb[j] = pe[j];
    }
    {
      int xid = x_tile[m * 256 + 2];
      const float* pe = emb + (size_t)xid * DIM + oct * 8;
#pragma unroll
      for (int j = 0; j < 8; j++) pf[0][j] = pe[j];
    }
    {
      int xid = x_tile[m * 256 + 3];
      const float* pe = emb + (size_t)xid * DIM + oct * 8;
#pragma unroll
      for (int j = 0; j < 8; j++) pf[1][j] = pe[j];
    }
    Frag8 pa, pb;
#pragma unroll
    for (int j = 0; j < 8; j++) { pa.us[j] = f2bf_bits(ta[j]); pb.us[j] = f2bf_bits(tb[j]); }
    *(int4*)&e_bf[0][dst] = pa.i4;
    *(int4*)&e_bf[1][dst] = pb.i4;
  }
  __syncthreads();

  if (!is_prod) {                      // xp[0] = e[0]@Wih^T (+bias via acc init)
    const int cw = wave - 4;
    f32x4 a0 = {bias1v2[0], bias1v2[0], bias1v2[0], bias1v2[0]};
    f32x4 a1 = {bias1v2[1], bias1v2[1], bias1v2[1], bias1v2[1]};
#pragma unroll
    for (int kt = 0; kt < 4; kt++) {
      int sw = (((kt * 4 + q) ^ l15) & 15) * 8;
      bf16x8 ae = *(const bf16x8*)&e_bf[0][l15 * 128 + sw];
      a0 = __builtin_amdgcn_mfma_f32_16x16x32_bf16(ae, wih[0][kt], a0, 0, 0, 0);
      a1 = __builtin_amdgcn_mfma_f32_16x16x32_bf16(ae, wih[1][kt], a1, 0, 0, 0);
    }
    *(f32x4*)&xp[0][(cw * 64 + lane) * 8]     = a0;
    *(f32x4*)&xp[0][(cw * 64 + lane) * 8 + 4] = a1;
  }
  __syncthreads();

#pragma unroll 2                       // static parities: pf[] stays in regs
  for (int t = 0; t <= S_LEN; t++) {
    if (is_prod) {
      if (t < S_LEN) {
        const int rb = (t + 1) & 1;    // h_{t-1}
        const int pt = wave * 64 + lane;
        // seed lo-chain with xp (saves epilogue adds; read early, latency ok)
        f32x4 al0 = *(const f32x4*)&xp[t & 1][pt * 8];
        f32x4 al1 = *(const f32x4*)&xp[t & 1][pt * 8 + 4];
        f32x4 ah0 = {0, 0, 0, 0}, ah1 = {0, 0, 0, 0};
#pragma unroll
        for (int kt = 0; kt < 4; kt++) {
          int sw = (((kt * 4 + q) ^ l15) & 15) * 8;
          bf16x8 ah = *(const bf16x8*)&h_bf[rb][l15 * 128 + sw];
          ah0 = __builtin_amdgcn_mfma_f32_16x16x32_bf16(ah, whi[0][kt], ah0, 0, 0, 0);
          ah1 = __builtin_amdgcn_mfma_f32_16x16x32_bf16(ah, whi[1][kt], ah1, 0, 0, 0);
          al0 = __builtin_amdgcn_mfma_f32_16x16x32_bf16(ah, wlo[0][kt], al0, 0, 0, 0);
          al1 = __builtin_amdgcn_mfma_f32_16x16x32_bf16(ah, wlo[1][kt], al1, 0, 0, 0);
        }
        const int wb = t & 1;          // h_t
#pragma unroll
        for (int ntL = 0; ntL < 2; ntL++) {
          int c = wave * 32 + ntL * 16 + l15;
          int oct = c >> 3;
#pragma unroll
          for (int r = 0; r < 4; r++) {  // D-layout: row = q*4 + r, col = l15
            int row = q * 4 + r;
            float av = ntL ? (ah1[r] + al1[r]) : (ah0[r] + al0[r]);
            h_bf[wb][row * 128 + ((oct ^ row) & 15) * 8 + (c & 7)] =
                (unsigned short)f2bf_rhu(tanh_fast(av));
          }
        }
      }
    } else {
      const int ti2 = tid - 256;
      const int m   = ti2 >> 4;
      const int oct = ti2 & 15;
      const int cw  = wave - 4;
      if (t + 2 < S_LEN) {             // stage e[t+2] (gathered at t-2)
        int4 pk;
        pk.x = pack_rhu(pf[t & 1][0], pf[t & 1][1]);
        pk.y = pack_rhu(pf[t & 1][2], pf[t & 1][3]);
        pk.z = pack_rhu(pf[t & 1][4], pf[t & 1][5]);
        pk.w = pack_rhu(pf[t & 1][6], pf[t & 1][7]);
        *(int4*)&e_bf[t & 1][m * 128 + ((oct ^ m) & 15) * 8] = pk;
      }
      if (t + 4 < S_LEN) {             // issue gather e[t+4] (2-step cover)
        int xid = x_tile[m * 256 + t + 4];
        const float* pe = emb + (size_t)xid * DIM + oct * 8;
#pragma unroll
        for (int j = 0; j < 8; j++) pf[t & 1][j] = pe[j];
      }
      if (t + 1 < S_LEN) {             // xp[t+1] = e[t+1]@Wih^T (+bias in init)
        f32x4 a0 = {bias1v2[0], bias1v2[0], bias1v2[0], bias1v2[0]};
        f32x4 a1 = {bias1v2[1], bias1v2[1], bias1v2[1], bias1v2[1]};
#pragma unroll
        for (int kt = 0; kt < 4; kt++) {
          int sw = (((kt * 4 + q) ^ l15) & 15) * 8;
          bf16x8 ae = *(const bf16x8*)&e_bf[(t + 1) & 1][l15 * 128 + sw];
          a0 = __builtin_amdgcn_mfma_f32_16x16x32_bf16(ae, wih[0][kt], a0, 0, 0, 0);
          a1 = __builtin_amdgcn_mfma_f32_16x16x32_bf16(ae, wih[1][kt], a1, 0, 0, 0);
        }
        *(f32x4*)&xp[(t + 1) & 1][(cw * 64 + lane) * 8]     = a0;
        *(f32x4*)&xp[(t + 1) & 1][(cw * 64 + lane) * 8 + 4] = a1;
      }
      if (t >= 1) {                    // LN1 fold -> RNN2 -> LN2 -> pool
        const int hb = (t - 1) & 1;
        Frag8 hr;
        hr.i4 = *(const int4*)&h_bf[hb][myrow * 128 + l15 * 8];
        float s = 0.f, sq = 0.f, d[5] = {0, 0, 0, 0, 0};
#pragma unroll
        for (int j = 0; j < 8; j++) {
          float v = bf2f_bits(hr.us[j]);
          s += v; sq += v * v;
#pragma unroll
          for (int jj = 0; jj < 5; jj++) d[jj] = fmaf(w2g[jj][j], v, d[jj]);
        }
        red_level7<0x124>(s, sq, d);   // one 4-level DPP butterfly, 7 values
        red_level7<0x128>(s, sq, d);
        red_level7<0x39>(s, sq, d);
        red_level7<0x4E>(s, sq, d);
        float mean = s * (1.f / 128.f);
        float var  = sq * (1.f / 128.f) - mean * mean;
        float rstd = rsqrtf(var + EPSL);
        float p[5];
#pragma unroll
        for (int jj = 0; jj < 5; jj++)   // exact fold of LN1+proj
          p[jj] = rstd * (d[jj] - mean * Gs[jj]) + Bs[jj];
        // lane l15 owns dim l15: select own p, matvec with own Whh2 row
        float psel = (l15 == 0) ? p[0] : (l15 == 1) ? p[1] :
                     (l15 == 2) ? p[2] : (l15 == 3) ? p[3] : p[4];
        float a = psel + t2_l;
#pragma unroll
        for (int jj = 0; jj < 5; jj++) a = fmaf(wrow[jj], h2rep[jj], a);
        float xn = tanh_fast(a);       // ONE tanh issue for all 5 dims
        // broadcast new h2 to all lanes (ds_swizzle, latency off-path)
        h2rep[0] = bcast16<0>(xn); h2rep[1] = bcast16<1>(xn);
        h2rep[2] = bcast16<2>(xn); h2rep[3] = bcast16<3>(xn);
        h2rep[4] = bcast16<4>(xn);
        float s2 = dpp_sum16(xn * validf) * 0.2f;           // mean over 5
        float dd = xn - s2;
        float v2 = dpp_sum16(dd * dd * validf) * 0.2f;      // var over 5
        float r2 = rsqrtf(v2 + EPSL);
        pool_l += dd * r2 * g2_l + be2_l;   // valid only l15<5; others junk
      }
    }
    // Raw barrier: drain LDS only; global gather loads stay in flight.
    asm volatile("s_waitcnt lgkmcnt(0)\n\ts_barrier" ::: "memory");
  }

  if (!is_prod) {                      // softmax over the 5 pool lanes
    float lg = pool_l * (1.f / 256.f);
    float mx = dpp_max16((l15 < 5) ? lg : -3.0e38f);
    float e  = (l15 < 5) ? __expf(lg - mx) : 0.f;
    float sm = dpp_sum16(e);
    if (l15 < 5) out[(size_t)(r0 + myrow) * 5 + l15] = e / sm;
  }
}

extern "C" void kernel_launch(void* const* d_in, const int* in_sizes, int n_in,
                              void* d_out, int out_size, void* d_ws, size_t ws_size,
                              hipStream_t stream) {
  (void)in_sizes; (void)n_in; (void)d_ws; (void)ws_size; (void)out_size;
  rnn_fused<<<dim3(64), dim3(512), 0, stream>>>(
      (const int*)  d_in[0],  (const float*)d_in[1],  (const float*)d_in[2],
      (const float*)d_in[3],  (const float*)d_in[4],  (const float*)d_in[5],
      (const float*)d_in[6],  (const float*)d_in[7],  (const float*)d_in[8],
      (const float*)d_in[9],  (const float*)d_in[10], (const float*)d_in[11],
      (const float*)d_in[12], (const float*)d_in[13], (float*)d_out);
}

// Round 6
// 295.682 us; speedup vs baseline: 2.1891x; 1.0993x over previous
//
#include <hip/hip_runtime.h>
#include <stdint.h>

#define S_LEN 256
#define DIM   128
#define EPSL  1e-5f

typedef __bf16 bf16x8 __attribute__((ext_vector_type(8)));
typedef float  f32x4  __attribute__((ext_vector_type(4)));

__device__ __forceinline__ unsigned short f2bf_bits(float f) {
  union { float f; unsigned int u; } v; v.f = f;
  unsigned int r = v.u + 0x7fffu + ((v.u >> 16) & 1u);   // RTNE (init paths)
  return (unsigned short)(r >> 16);
}
__device__ __forceinline__ float bf2f_bits(unsigned short b) {
  union { float f; unsigned int u; } v; v.u = ((unsigned int)b) << 16; return v.f;
}
// Hot-path bf16 round-half-up: 2 VALU ops.
__device__ __forceinline__ unsigned f2bf_rhu(float f) {
  return (__float_as_uint(f) + 0x8000u) >> 16;
}
// Pack two floats -> (bf16 lo, bf16 hi) in one u32: 2 adds + 1 v_perm.
__device__ __forceinline__ unsigned pack_rhu(float lo, float hi) {
  return __builtin_amdgcn_perm(__float_as_uint(hi) + 0x8000u,
                               __float_as_uint(lo) + 0x8000u, 0x07060302u);
}
// tanh(x) = 1 - 2/(e^{2x}+1): ~1e-6 rel err, exact at +-inf.
__device__ __forceinline__ float tanh_fast(float x) {
  float e = __expf(2.f * x);
  return 1.f - 2.f * __builtin_amdgcn_rcpf(e + 1.f);
}

// VALU cross-lane via DPP rotation; 16-lane reduce visible on all lanes.
template<int CTRL>
__device__ __forceinline__ float dpp_rot_add(float v) {
  int r = __builtin_amdgcn_update_dpp(0, __float_as_int(v), CTRL, 0xF, 0xF, true);
  return v + __int_as_float(r);
}
template<int CTRL>
__device__ __forceinline__ float dpp_rot_max(float v) {
  int r = __builtin_amdgcn_update_dpp(0, __float_as_int(v), CTRL, 0xF, 0xF, true);
  return fmaxf(v, __int_as_float(r));
}
__device__ __forceinline__ float dpp_sum16(float v) {
  v = dpp_rot_add<0x124>(v); v = dpp_rot_add<0x128>(v);
  v = dpp_rot_add<0x39>(v);  v = dpp_rot_add<0x4E>(v);
  return v;
}
__device__ __forceinline__ float dpp_max16(float v) {
  v = dpp_rot_max<0x124>(v); v = dpp_rot_max<0x128>(v);
  v = dpp_rot_max<0x39>(v);  v = dpp_rot_max<0x4E>(v);
  return v;
}
template<int CTRL>
__device__ __forceinline__ void red_level7(float& s, float& sq, float* d) {
  s  = dpp_rot_add<CTRL>(s);
  sq = dpp_rot_add<CTRL>(sq);
#pragma unroll
  for (int j = 0; j < 5; j++) d[j] = dpp_rot_add<CTRL>(d[j]);
}
// Broadcast lane JJ of each 16-group to its whole group.
template<int JJ>
__device__ __forceinline__ float bcast16(float v) {
  int r = __builtin_amdgcn_ds_swizzle(__float_as_int(v), (JJ << 5) | 0x10);
  return __int_as_float(r);
}

union Frag8 { unsigned short us[8]; bf16x8 v; int4 i4; };

// HOMOGENEOUS waves: each of the 8 waves owns n-tile [wave*16, wave*16+16) and
// per step does 8 h@Whh MFMA (hi+lo split) + 4 e@Wih MFMA for t+1 whose result
// STAYS IN REGISTERS (seeds next step's lo accumulator -- no xp LDS ring).
// Side roles (off the serial chain): waves 0-3 LN1/RNN2/LN2/pool on h_{t-1};
// waves 4-7 e-gather + staging. One raw lgkm-only barrier per step.
__global__ __launch_bounds__(512, 2)
void rnn_fused(const int* __restrict__ x,
               const float* __restrict__ emb,
               const float* __restrict__ Wih1,
               const float* __restrict__ bih1,
               const float* __restrict__ Whh1,
               const float* __restrict__ bhh1,
               const float* __restrict__ g1,
               const float* __restrict__ be1,
               const float* __restrict__ Wih2,
               const float* __restrict__ bih2,
               const float* __restrict__ Whh2,
               const float* __restrict__ bhh2,
               const float* __restrict__ g2,
               const float* __restrict__ be2,
               float* __restrict__ out)
{
  // h/e element (row m, channel c) at m*128 + ((c>>3) ^ (m&15))*8 + (c&7)
  __shared__ __align__(16) unsigned short h_bf[2][16 * 128];   // 8 KB
  __shared__ __align__(16) unsigned short e_bf[2][16 * 128];   // 8 KB
  __shared__ int x_tile[16 * 256];                             // 16 KB

  const int tid  = threadIdx.x;
  const int wave = tid >> 6;
  const int lane = tid & 63;
  const int r0   = blockIdx.x * 16;
  const int l15  = lane & 15;
  const int q    = lane >> 4;

  for (int i = tid; i < 16 * 256; i += 512)
    x_tile[i] = x[(size_t)(r0 + (i >> 8)) * S_LEN + (i & 255)];
  for (int i = tid; i < 16 * 128; i += 512) h_bf[1][i] = 0;   // h_{-1} = 0

  // ---- core weights: every wave owns n-tile n0 = wave*16 ----
  const int n1 = wave * 16 + l15;
  const float bias1v = bih1[n1] + bhh1[n1];
  bf16x8 whi[4], wlo[4], wih[4];
#pragma unroll
  for (int kt = 0; kt < 4; kt++) {
    int k0 = kt * 32 + q * 8;
    Frag8 fh, fl, fa;
#pragma unroll
    for (int j = 0; j < 8; j++) {
      float w = Whh1[n1 * DIM + k0 + j];
      unsigned short hi = f2bf_bits(w);
      fh.us[j] = hi;
      fl.us[j] = f2bf_bits(w - bf2f_bits(hi));     // split-bf16 compensation
      fa.us[j] = f2bf_bits(Wih1[n1 * DIM + k0 + j]);
    }
    whi[kt] = fh.v; wlo[kt] = fl.v; wih[kt] = fa.v;
  }

  const bool ln_role = (wave < 4);
  // ---- LN/RNN2 state (waves 0-3) ----
  float w2g[5][8], Gs[5], Bs[5], wrow[5];
  float t2_l = 0.f, g2_l = 0.f, be2_l = 0.f, validf = 0.f;
  float h2rep[5], pool_l = 0.f;
  int myrow = 0;
  // ---- staging state (waves 4-7) ----
  float pf[2][8];
  const int gm   = (wave & 3) * 4 + q;   // staged row (waves 4-7)
  const int goct = l15;                  // staged oct
  const int gdst = gm * 128 + ((goct ^ gm) & 15) * 8;

  if (ln_role) {
    myrow = wave * 4 + q;
    int coct = (l15 ^ myrow) & 15;       // storage oct l15 -> channels coct*8..+7
#pragma unroll
    for (int j = 0; j < 8; j++) {
      int c = coct * 8 + j;
      float gc = g1[c];
#pragma unroll
      for (int jj = 0; jj < 5; jj++) w2g[jj][j] = Wih2[jj * DIM + c] * gc;
    }
#pragma unroll
    for (int jj = 0; jj < 5; jj++) { Gs[jj] = 0.f; Bs[jj] = 0.f; }
    for (int c = 0; c < DIM; c++) {      // init-only scalar loop
      float gc = g1[c], bc = be1[c];
#pragma unroll
      for (int jj = 0; jj < 5; jj++) {
        float w = Wih2[jj * DIM + c];
        Gs[jj] += w * gc; Bs[jj] += w * bc;
      }
    }
    validf = (l15 < 5) ? 1.f : 0.f;
    if (l15 < 5) {
      t2_l = bih2[l15] + bhh2[l15];
      g2_l = g2[l15]; be2_l = be2[l15];
#pragma unroll
      for (int jj = 0; jj < 5; jj++) wrow[jj] = Whh2[l15 * 5 + jj];
    } else {
#pragma unroll
      for (int jj = 0; jj < 5; jj++) wrow[jj] = 0.f;
    }
#pragma unroll
    for (int jj = 0; jj < 5; jj++) h2rep[jj] = 0.f;
  }

  __syncthreads();

  if (!ln_role) {                        // stage e[0],e[1]; preload pf=e[2],e[3]
    float ta[8], tb[8];
    {
      int xid = x_tile[gm * 256 + 0];
      const float* pe = emb + (size_t)xid * DIM + goct * 8;
#pragma unroll
      for (int j = 0; j < 8; j++) ta[j] = pe[j];
    }
    {
      int xid = x_tile[gm * 256 + 1];
      const float* pe = emb + (size_t)xid * DIM + goct * 8;
#pragma unroll
      for (int j = 0; j < 8; j++) tb[j] = pe[j];
    }
    {
      int xid = x_tile[gm * 256 + 2];
      const float* pe = emb + (size_t)xid * DIM + goct * 8;
#pragma unroll
      for (int j = 0; j < 8; j++) pf[0][j] = pe[j];
    }
    {
      int xid = x_tile[gm * 256 + 3];
      const float* pe = emb + (size_t)xid * DIM + goct * 8;
#pragma unroll
      for (int j = 0; j < 8; j++) pf[1][j] = pe[j];
    }
    Frag8 pa, pb;
#pragma unroll
    for (int j = 0; j < 8; j++) { pa.us[j] = f2bf_bits(ta[j]); pb.us[j] = f2bf_bits(tb[j]); }
    *(int4*)&e_bf[0][gdst] = pa.i4;
    *(int4*)&e_bf[1][gdst] = pb.i4;
  }
  __syncthreads();

  // xpacc = e[0]@Wih^T + bias for this wave's n-tile (register handoff)
  f32x4 xpacc = {bias1v, bias1v, bias1v, bias1v};
#pragma unroll
  for (int kt = 0; kt < 4; kt++) {
    int sw = (((kt * 4 + q) ^ l15) & 15) * 8;
    bf16x8 ae = *(const bf16x8*)&e_bf[0][l15 * 128 + sw];
    xpacc = __builtin_amdgcn_mfma_f32_16x16x32_bf16(ae, wih[kt], xpacc, 0, 0, 0);
  }
  // protects e_bf[0] read above vs t=0 staging write below
  asm volatile("s_waitcnt lgkmcnt(0)\n\ts_barrier" ::: "memory");

#pragma unroll 2                         // static parities: pf[] stays in regs
  for (int t = 0; t <= S_LEN; t++) {
    f32x4 ah = {0.f, 0.f, 0.f, 0.f};
    f32x4 al = xpacc;                    // e_t@Wih + bias, from last step's regs
    if (t < S_LEN) {                     // ---- serial core: h_t for my n-tile
      const int rb = (t + 1) & 1;        // h_{t-1}
#pragma unroll
      for (int kt = 0; kt < 4; kt++) {
        int sw = (((kt * 4 + q) ^ l15) & 15) * 8;
        bf16x8 ahf = *(const bf16x8*)&h_bf[rb][l15 * 128 + sw];
        ah = __builtin_amdgcn_mfma_f32_16x16x32_bf16(ahf, whi[kt], ah, 0, 0, 0);
        al = __builtin_amdgcn_mfma_f32_16x16x32_bf16(ahf, wlo[kt], al, 0, 0, 0);
      }
    }
    if (t + 1 < S_LEN) {                 // ---- e_{t+1}@Wih into regs (off-chain)
      f32x4 a = {bias1v, bias1v, bias1v, bias1v};
#pragma unroll
      for (int kt = 0; kt < 4; kt++) {
        int sw = (((kt * 4 + q) ^ l15) & 15) * 8;
        bf16x8 ae = *(const bf16x8*)&e_bf[(t + 1) & 1][l15 * 128 + sw];
        a = __builtin_amdgcn_mfma_f32_16x16x32_bf16(ae, wih[kt], a, 0, 0, 0);
      }
      xpacc = a;
    }
    if (t < S_LEN) {                     // ---- epilogue: 4 tanh, 4 b16 writes
      const int wb = t & 1;
      const int c = wave * 16 + l15;
      const int oct = c >> 3;
#pragma unroll
      for (int r = 0; r < 4; r++) {      // D-layout: row = q*4 + r, col = l15
        int row = q * 4 + r;
        float av = ah[r] + al[r];
        h_bf[wb][row * 128 + ((oct ^ row) & 15) * 8 + (c & 7)] =
            (unsigned short)f2bf_rhu(tanh_fast(av));
      }
    }
    if (!ln_role) {                      // ---- staging role (waves 4-7)
      if (t + 2 < S_LEN) {               // stage e[t+2] (gathered at t-2)
        int4 pk;
        pk.x = pack_rhu(pf[t & 1][0], pf[t & 1][1]);
        pk.y = pack_rhu(pf[t & 1][2], pf[t & 1][3]);
        pk.z = pack_rhu(pf[t & 1][4], pf[t & 1][5]);
        pk.w = pack_rhu(pf[t & 1][6], pf[t & 1][7]);
        *(int4*)&e_bf[t & 1][gdst] = pk;
      }
      if (t + 4 < S_LEN) {               // issue gather e[t+4] (2-step cover)
        int xid = x_tile[gm * 256 + t + 4];
        const float* pe = emb + (size_t)xid * DIM + goct * 8;
#pragma unroll
        for (int j = 0; j < 8; j++) pf[t & 1][j] = pe[j];
      }
    } else if (t >= 1) {                 // ---- LN role (waves 0-3), h_{t-1}
      const int hb = (t - 1) & 1;
      Frag8 hr;
      hr.i4 = *(const int4*)&h_bf[hb][myrow * 128 + l15 * 8];
      float s = 0.f, sq = 0.f, d[5] = {0, 0, 0, 0, 0};
#pragma unroll
      for (int j = 0; j < 8; j++) {
        float v = bf2f_bits(hr.us[j]);
        s += v; sq += v * v;
#pragma unroll
        for (int jj = 0; jj < 5; jj++) d[jj] = fmaf(w2g[jj][j], v, d[jj]);
      }
      red_level7<0x124>(s, sq, d);       // one 4-level DPP butterfly, 7 values
      red_level7<0x128>(s, sq, d);
      red_level7<0x39>(s, sq, d);
      red_level7<0x4E>(s, sq, d);
      float mean = s * (1.f / 128.f);
      float var  = sq * (1.f / 128.f) - mean * mean;
      float rstd = rsqrtf(var + EPSL);
      float p[5];
#pragma unroll
      for (int jj = 0; jj < 5; jj++)     // exact fold of LN1+proj
        p[jj] = rstd * (d[jj] - mean * Gs[jj]) + Bs[jj];
      float psel = (l15 == 0) ? p[0] : (l15 == 1) ? p[1] :
                   (l15 == 2) ? p[2] : (l15 == 3) ? p[3] : p[4];
      float a = psel + t2_l;
#pragma unroll
      for (int jj = 0; jj < 5; jj++) a = fmaf(wrow[jj], h2rep[jj], a);
      float xn = tanh_fast(a);           // one tanh issue for all 5 dims
      h2rep[0] = bcast16<0>(xn); h2rep[1] = bcast16<1>(xn);
      h2rep[2] = bcast16<2>(xn); h2rep[3] = bcast16<3>(xn);
      h2rep[4] = bcast16<4>(xn);
      float s2 = dpp_sum16(xn * validf) * 0.2f;        // mean over 5
      float dd = xn - s2;
      float v2 = dpp_sum16(dd * dd * validf) * 0.2f;   // var over 5
      float r2 = rsqrtf(v2 + EPSL);
      pool_l += dd * r2 * g2_l + be2_l;  // valid only l15<5
    }
    // Raw barrier: drain LDS only; global gather loads stay in flight.
    asm volatile("s_waitcnt lgkmcnt(0)\n\ts_barrier" ::: "memory");
  }

  if (ln_role) {                         // softmax over the 5 pool lanes
    float lg = pool_l * (1.f / 256.f);
    float mx = dpp_max16((l15 < 5) ? lg : -3.0e38f);
    float e  = (l15 < 5) ? __expf(lg - mx) : 0.f;
    float sm = dpp_sum16(e);
    if (l15 < 5) out[(size_t)(r0 + myrow) * 5 + l15] = e / sm;
  }
}

extern "C" void kernel_launch(void* const* d_in, const int* in_sizes, int n_in,
                              void* d_out, int out_size, void* d_ws, size_t ws_size,
                              hipStream_t stream) {
  (void)in_sizes; (void)n_in; (void)d_ws; (void)ws_size; (void)out_size;
  rnn_fused<<<dim3(64), dim3(512), 0, stream>>>(
      (const int*)  d_in[0],  (const float*)d_in[1],  (const float*)d_in[2],
      (const float*)d_in[3],  (const float*)d_in[4],  (const float*)d_in[5],
      (const float*)d_in[6],  (const float*)d_in[7],  (const float*)d_in[8],
      (const float*)d_in[9],  (const float*)d_in[10], (const float*)d_in[11],
      (const float*)d_in[12], (const float*)d_in[13], (float*)d_out);
}